// Round 16
// baseline (334.280 us; speedup 1.0000x reference)
//
#include <hip/hip_runtime.h>

#define GRID 128
#define TPB 256
#define SLICE 32          // memory rows per block
#define BB 4
#define DD 256
#define NN 1024
#define MM 256
#define KSH 3
#define RPL 265   // M+K+6
#define WPL 775   // 3M+K+4
#define TS 32
#define EPSF 1e-12f

struct KArgs {
    const float *ctrl, *rW, *rb, *wW, *wb;
    const float *memory0, *prec0, *read_w0, *write_w0;
    float *out;
    float *rp, *wp;                        // params: cached (published once via fenced barrier)
    float *cosr, *cosw, *wbuf, *rdw;       // [2][B][N] parity double-buffered, LLC-coherent access
    float *csp, *dsp;                      // [2][GRID][TS]
    float *rdp;                            // [2][GRID][MM] coalesced
    unsigned *flagsA, *flagsB;
};

// LLC-coherent scalar access (sc0 sc1): bypasses non-coherent L1/L2, no fences needed.
__device__ __forceinline__ float cload(const float* p){
    return __hip_atomic_load(p, __ATOMIC_RELAXED, __HIP_MEMORY_SCOPE_SYSTEM);
}
__device__ __forceinline__ void cstore(float* p, float v){
    __hip_atomic_store(p, v, __ATOMIC_RELAXED, __HIP_MEMORY_SCOPE_SYSTEM);
}

__device__ __forceinline__ float softplusf(float x){
    return fmaxf(x, 0.0f) + log1pf(expf(-fabsf(x)));
}
__device__ __forceinline__ float sigmoidf(float x){
    return 1.0f / (1.0f + expf(-x));
}

// arrive: publish own flag (syncthreads drains vmcnt -> cstores LLC-visible first)
template <bool FENCE>
__device__ __forceinline__ void garrive(unsigned* flags, unsigned gen, int g, int tid){
    __syncthreads();
    if (tid == 0){
        if (FENCE) __builtin_amdgcn_fence(__ATOMIC_RELEASE, "agent");
        __hip_atomic_store(&flags[g*16], gen, __ATOMIC_RELAXED, __HIP_MEMORY_SCOPE_SYSTEM);
    }
}
// global block-wide wait (prologue/epilogue only)
template <bool FENCE>
__device__ __forceinline__ void gwait(unsigned* flags, unsigned gen, int tid){
    if (tid < 64){
        while (1){
            unsigned f0 = __hip_atomic_load(&flags[tid*16], __ATOMIC_RELAXED, __HIP_MEMORY_SCOPE_SYSTEM);
            unsigned f1 = __hip_atomic_load(&flags[(tid+64)*16], __ATOMIC_RELAXED, __HIP_MEMORY_SCOPE_SYSTEM);
            if (__all(f0 >= gen && f1 >= gen)) break;
            __builtin_amdgcn_s_sleep(1);
        }
    }
    __syncthreads();
    if (FENCE) __builtin_amdgcn_fence(__ATOMIC_ACQUIRE, "agent");
    asm volatile("" ::: "memory");
}
// WAVE-LOCAL waits (no syncthreads): each wave proceeds as soon as its deps are in.
__device__ __forceinline__ void waitA_wave(unsigned* flags, unsigned gen, int b, int lane){
    int idx = b*32 + (lane & 31);   // batch-local: straggler set 32
    while (1){
        unsigned f = __hip_atomic_load(&flags[idx*16], __ATOMIC_RELAXED, __HIP_MEMORY_SCOPE_SYSTEM);
        if (__all(f >= gen)) break;
        __builtin_amdgcn_s_sleep(1);
    }
    asm volatile("" ::: "memory");
}
__device__ __forceinline__ void waitB_wave(unsigned* flags, unsigned gen, int lane){
    while (1){
        unsigned f0 = __hip_atomic_load(&flags[lane*16], __ATOMIC_RELAXED, __HIP_MEMORY_SCOPE_SYSTEM);
        unsigned f1 = __hip_atomic_load(&flags[(lane+64)*16], __ATOMIC_RELAXED, __HIP_MEMORY_SCOPE_SYSTEM);
        if (__all(f0 >= gen && f1 >= gen)) break;
        __builtin_amdgcn_s_sleep(1);
    }
    asm volatile("" ::: "memory");
}

// full-block reductions (prologue addressing only)
__device__ __forceinline__ float blk_sum(float v, float* s4, int tid){
    #pragma unroll
    for (int off = 32; off; off >>= 1) v += __shfl_down(v, off);
    if ((tid & 63) == 0) s4[tid >> 6] = v;
    __syncthreads();
    float r = s4[0] + s4[1] + s4[2] + s4[3];
    __syncthreads();
    return r;
}

// full-block addressing (prologue t=0 write-addr only); 4 elems/thread
__device__ __forceinline__ void addr_core2(const float cosx[4], const float prev[4],
                                           const float* __restrict__ p,
                                           float* s4, float* wg, int tid,
                                           float out_wc[4]){
    float beta_p  = softplusf(p[MM]);
    float g       = sigmoidf(p[MM+1]);
    float s0r = p[MM+2], s1r = p[MM+3], s2r = p[MM+4];
    float smx = fmaxf(s0r, fmaxf(s1r, s2r));
    float e0 = expf(s0r-smx), e1 = expf(s1r-smx), e2 = expf(s2r-smx);
    float sden = e0+e1+e2;
    float s0 = e0/sden, s1 = e1/sden, s2 = e2/sden;
    float gamma_p = 1.0f + softplusf(p[MM+2+KSH]);
    // bmax := beta_p (>= max beta_p*cos, shift-invariant, no reduction needed)
    float ev[4]; float ls = 0.0f;
    #pragma unroll
    for (int q = 0; q < 4; q++){ ev[q] = expf(beta_p*cosx[q] - beta_p); ls += ev[q]; }
    float bs = blk_sum(ls, s4, tid);
    float invb = 1.0f / bs;
    #pragma unroll
    for (int q = 0; q < 4; q++){
        int i = tid + q*256;
        wg[i] = g*(ev[q]*invb) + (1.0f-g)*prev[q];
    }
    __syncthreads();
    float wt[4]; float lps = 0.0f;
    #pragma unroll
    for (int q = 0; q < 4; q++){
        int i = tid + q*256;
        float sh = s0*wg[(i+1)&(NN-1)] + s1*wg[i] + s2*wg[(i-1)&(NN-1)];
        wt[q] = exp2f(gamma_p * log2f(sh + EPSF));
        lps += wt[q];
    }
    float ts = blk_sum(lps, s4, tid);
    float inv = 1.0f / (ts + EPSF);
    #pragma unroll
    for (int q = 0; q < 4; q++) out_wc[q] = wt[q] * inv;
    __syncthreads();
}

// WAVE-LOCAL full-N addressing: 16 consecutive elems/lane, zero syncthreads.
// Sums via shfl_xor butterflies; the +-1 circular shift via boundary shuffles
// (lane l's wg[15] -> lane l+1's left edge; wraps handle mod-N exactly).
__device__ __forceinline__ void wave_addr(const float* __restrict__ p,
                                          const float* cos_src,
                                          const float* prev_src, const float* prev_src0,
                                          int use0, int lane, float out_w[16]){
    float beta_p  = softplusf(p[MM]);
    float g       = sigmoidf(p[MM+1]);
    float s0r = p[MM+2], s1r = p[MM+3], s2r = p[MM+4];
    float smx = fmaxf(s0r, fmaxf(s1r, s2r));
    float e0 = expf(s0r-smx), e1 = expf(s1r-smx), e2 = expf(s2r-smx);
    float sden = e0+e1+e2;
    float s0 = e0/sden, s1 = e1/sden, s2 = e2/sden;
    float gamma_p = 1.0f + softplusf(p[MM+2+KSH]);
    const int i0 = lane*16;
    float ev[16], prev[16]; float ls = 0.0f;
    #pragma unroll
    for (int k = 0; k < 16; k++){
        float cx = cload(&cos_src[i0+k]);
        prev[k] = use0 ? prev_src0[i0+k] : cload(&prev_src[i0+k]);
        ev[k] = expf(beta_p*cx - beta_p);   // bmax := beta_p (shift-invariant)
        ls += ev[k];
    }
    #pragma unroll
    for (int off = 32; off; off >>= 1) ls += __shfl_xor(ls, off);
    float invb = 1.0f / ls;
    float wg[16];
    #pragma unroll
    for (int k = 0; k < 16; k++) wg[k] = g*(ev[k]*invb) + (1.0f-g)*prev[k];
    float wgL = __shfl(wg[15], (lane+63)&63);   // wg[i0-1]  (mod N via wrap)
    float wgR = __shfl(wg[0],  (lane+ 1)&63);   // wg[i0+16]
    float lps = 0.0f;
    #pragma unroll
    for (int k = 0; k < 16; k++){
        float lv = (k == 0 ) ? wgL : wg[k-1];
        float rv = (k == 15) ? wgR : wg[k+1];
        float sh = s0*rv + s1*wg[k] + s2*lv;
        out_w[k] = exp2f(gamma_p * log2f(sh + EPSF));
        lps += out_w[k];
    }
    #pragma unroll
    for (int off = 32; off; off >>= 1) lps += __shfl_xor(lps, off);
    float inv = 1.0f / (lps + EPSF);
    #pragma unroll
    for (int k = 0; k < 16; k++) out_w[k] *= inv;
}

// Tail work for step `tnext` (r10 measured-best version, unchanged).
__device__ __forceinline__ void tail_cos(const KArgs& a, int tnext, int b, int g, int ns0,
        float (*lmem)[MM], float (*skey)[MM],
        const float* lwn, const float* rdvec, int tid){
    if (rdvec){
        float accv = 0.f;
        #pragma unroll 8
        for (int j = 0; j < SLICE; j++) accv += rdvec[j]*lmem[j][tid];
        cstore(&a.rdp[(size_t)((tnext-1)&1)*GRID*MM + g*MM + tid], accv);
    }
    const float* kr = a.rp + (size_t)tnext*BB*RPL + (size_t)b*RPL;
    const bool hw = (tnext+1 <= TS-1);
    const float* kwp = a.wp + (size_t)(hw ? tnext+1 : tnext)*BB*WPL + (size_t)b*WPL;
    skey[0][tid] = kr[tid];
    skey[1][tid] = kwp[tid];
    __syncthreads();   // rdvec reads + skey staged before lmem overwrite
    {
        const float* pw = a.wp + (size_t)tnext*BB*WPL + (size_t)b*WPL;
        float e = pw[MM+3+KSH + tid];       // pre-sigmoided erase
        float d = pw[2*MM+3+KSH + tid];
        #pragma unroll 8
        for (int j = 0; j < SLICE; j++){
            float w = lwn[j];
            lmem[j][tid] = lmem[j][tid]*(1.0f - w*e) + w*d;
        }
    }
    __syncthreads();
    {
        int j = tid >> 3, c = tid & 7;
        float dr=0.f, dw=0.f, nm=0.f, nr=0.f, nk=0.f;
        #pragma unroll
        for (int m = 0; m < 8; m++){
            int col = c*4 + m*32;
            float4 mv = *(const float4*)&lmem[j][col];
            float4 rv = *(const float4*)&skey[0][col];
            float4 wv = *(const float4*)&skey[1][col];
            dr += mv.x*rv.x + mv.y*rv.y + mv.z*rv.z + mv.w*rv.w;
            dw += mv.x*wv.x + mv.y*wv.y + mv.z*wv.z + mv.w*wv.w;
            nm += mv.x*mv.x + mv.y*mv.y + mv.z*mv.z + mv.w*mv.w;
            nr += rv.x*rv.x + rv.y*rv.y + rv.z*rv.z + rv.w*rv.w;
            nk += wv.x*wv.x + wv.y*wv.y + wv.z*wv.z + wv.w*wv.w;
        }
        #pragma unroll
        for (int off = 4; off; off >>= 1){
            dr += __shfl_down(dr, off); dw += __shfl_down(dw, off);
            nm += __shfl_down(nm, off); nr += __shfl_down(nr, off);
            nk += __shfl_down(nk, off);
        }
        if (c == 0){
            float sn = sqrtf(nm) + EPSF;
            int n = ns0 + j;
            cstore(&a.cosr[(size_t)(tnext&1)*BB*NN + b*NN + n], dr/(sn*(sqrtf(nr)+EPSF)));
            if (hw) cstore(&a.cosw[(size_t)((tnext+1)&1)*BB*NN + b*NN + n], dw/(sn*(sqrtf(nk)+EPSF)));
        }
    }
}

// tail part 2: A/W scale+append, cs/ds partials publish (r10 version).
__device__ __forceinline__ void tail_links(const KArgs& a, int tnext, int g,
        float (*lA)[SLICE], float (*lW)[SLICE],
        const float* lwn, const float* rvec, const float* lprec, int tid){
    for (int p2 = tid; p2 < tnext*SLICE; p2 += TPB){
        int s = p2 >> 5, jj = p2 & 31;
        lA[s][jj] *= (1.0f - lwn[jj]);
    }
    __syncthreads();
    if (tid < SLICE){ lA[tnext][tid] = lprec[tid]; lW[tnext][tid] = lwn[tid]; }
    __syncthreads();
    int s = tid >> 3, c = tid & 7;
    if (s <= tnext){
        float pc = 0.f, pd = 0.f;
        #pragma unroll
        for (int q = 0; q < 4; q++){
            int jj = c*4 + q;
            float r = rvec[jj];
            pc += r*lA[s][jj];
            pd += r*lW[s][jj];
        }
        #pragma unroll
        for (int off = 4; off; off >>= 1){ pc += __shfl_down(pc, off); pd += __shfl_down(pd, off); }
        if (c == 0){
            cstore(&a.csp[(size_t)(tnext&1)*GRID*TS + g*TS + s], pc);
            cstore(&a.dsp[(size_t)(tnext&1)*GRID*TS + g*TS + s], pd);
        }
    }
}

__global__ void __launch_bounds__(TPB) kfull(KArgs a){
    const int g   = blockIdx.x;
    const int tid = threadIdx.x;
    const int wvi = tid >> 6, lane = tid & 63;
    const int b   = g >> 5;             // batch
    const int sl  = g & 31;             // slice index within batch
    const int ns0 = sl * SLICE;         // first row of slice
    const int sq    = sl >> 3;          // full-block layout slice q (prologue)
    const int sbase = (sl & 7) * 32;
    const int lbase = sl * 2;           // wave layout: first lane owning own slice

    __shared__ __align__(16) float lmem[SLICE][MM];   // 32 KB memory slice
    __shared__ __align__(16) float skey[2][MM];
    __shared__ __align__(16) float lA[TS][SLICE];
    __shared__ __align__(16) float lW[TS][SLICE];
    __shared__ float wgA[NN];                         // prologue addr scratch
    __shared__ float s8[8];
    __shared__ float spi[4];                          // pi0,pi1,pi2, ag
    __shared__ float swcf_r[SLICE], swcf_w[SLICE];
    __shared__ float lprec[SLICE], lr_old[SLICE], lw_old[SLICE];
    __shared__ float lrn[SLICE], lwn[SLICE], lbw[SLICE], lfw[SLICE];

    // ===== Phase A: projections (cached stores; published by fenced barrier) =====
    {
        const int tt = g >> 2;
        for (int o = tid; o < BB*DD; o += TPB) wgA[o] = a.ctrl[(size_t)tt*BB*DD + o];
        __syncthreads();
        for (int half = 0; half < 2; half++){
            int jc = (g & 3) + half*4;
            int j = jc*130 + tid;
            if (tid < 130 && j < RPL + WPL){
                const float* wrow; float bias; int isw, jj;
                if (j < RPL){ jj = j;       wrow = a.rW + (size_t)jj*DD; bias = a.rb[jj]; isw = 0; }
                else        { jj = j - RPL; wrow = a.wW + (size_t)jj*DD; bias = a.wb[jj]; isw = 1; }
                const float4* w4 = (const float4*)wrow;
                float a0 = bias, a1 = bias, a2 = bias, a3 = bias;
                for (int d = 0; d < DD/4; d++){
                    float4 wv = w4[d];
                    float4 c0 = *(const float4*)&wgA[0*DD + d*4];
                    float4 c1 = *(const float4*)&wgA[1*DD + d*4];
                    float4 c2 = *(const float4*)&wgA[2*DD + d*4];
                    float4 c3 = *(const float4*)&wgA[3*DD + d*4];
                    a0 += wv.x*c0.x + wv.y*c0.y + wv.z*c0.z + wv.w*c0.w;
                    a1 += wv.x*c1.x + wv.y*c1.y + wv.z*c1.z + wv.w*c1.w;
                    a2 += wv.x*c2.x + wv.y*c2.y + wv.z*c2.z + wv.w*c2.w;
                    a3 += wv.x*c3.x + wv.y*c3.y + wv.z*c3.z + wv.w*c3.w;
                }
                if (isw && jj >= MM+3+KSH && jj < 2*MM+3+KSH){  // erase -> sigmoid once
                    a0 = sigmoidf(a0); a1 = sigmoidf(a1); a2 = sigmoidf(a2); a3 = sigmoidf(a3);
                }
                if (!isw){
                    float* dst = a.rp + (size_t)tt*BB*RPL;
                    dst[0*RPL+jj]=a0; dst[1*RPL+jj]=a1; dst[2*RPL+jj]=a2; dst[3*RPL+jj]=a3;
                } else {
                    float* dst = a.wp + (size_t)tt*BB*WPL;
                    dst[0*WPL+jj]=a0; dst[1*WPL+jj]=a1; dst[2*WPL+jj]=a2; dst[3*WPL+jj]=a3;
                }
            }
        }
    }
    garrive<true>(a.flagsA, 1, g, tid);
    gwait<true>(a.flagsA, 1, tid);

    // ===== Phase B: memory0 -> LDS, cos_w^0 -> cosw[0], state init =====
    {
        const float* kw = a.wp + (size_t)b*WPL;   // t=0 write key
        const int m0 = lane*4;
        float k0=kw[m0], k1=kw[m0+1], k2=kw[m0+2], k3=kw[m0+3];
        float nk = k0*k0 + k1*k1 + k2*k2 + k3*k3;
        #pragma unroll
        for (int off = 32; off; off >>= 1) nk += __shfl_down(nk, off);
        nk = __shfl(nk, 0);
        float snk = sqrtf(nk) + EPSF;
        for (int rr = 0; rr < 8; rr++){
            int j = wvi*8 + rr, n = ns0 + j;
            float4 m4 = ((const float4*)a.memory0)[((size_t)(b*NN+n))*64 + lane];
            *(float4*)&lmem[j][m0] = m4;
            float dw = m4.x*k0 + m4.y*k1 + m4.z*k2 + m4.w*k3;
            float nm = m4.x*m4.x + m4.y*m4.y + m4.z*m4.z + m4.w*m4.w;
            #pragma unroll
            for (int off = 32; off; off >>= 1){ dw += __shfl_down(dw, off); nm += __shfl_down(nm, off); }
            if (lane == 0) cstore(&a.cosw[0*BB*NN + b*NN + n], dw / ((sqrtf(nm)+EPSF)*snk));
        }
        if (tid < SLICE){
            lprec[tid]  = a.prec0[b*NN + ns0 + tid];
            lr_old[tid] = a.read_w0[b*NN + ns0 + tid];
        }
    }
    garrive<false>(a.flagsA, 2, g, tid);
    gwait<false>(a.flagsA, 2, tid);

    // ===== Phase C: redundant write-addr_0 + tail(0) =====
    {
        const float* p = a.wp + (size_t)b*WPL;
        float cosx[4], prev[4], wcf[4];
        #pragma unroll
        for (int q = 0; q < 4; q++){
            int i = tid + q*256;
            cosx[q] = cload(&a.cosw[0*BB*NN + b*NN + i]);
            prev[q] = a.write_w0[b*NN + i];
        }
        addr_core2(cosx, prev, p, s8, wgA, tid, wcf);
        float ag = sigmoidf(p[3*MM+3+KSH]);
        if (tid >= sbase && tid < sbase+32){
            int j = tid - sbase;
            float v = (1.0f - ag)*wcf[sq];      // alloc == 0 exactly
            lwn[j] = v;
            cstore(&a.wbuf[0*BB*NN + b*NN + ns0 + j], v);
        }
        __syncthreads();
        tail_cos(a, 0, b, g, ns0, lmem, skey, lwn, nullptr, tid);
        garrive<false>(a.flagsA, 3, g, tid);
        tail_links(a, 0, g, lA, lW, lwn, lr_old, lprec, tid);
        garrive<false>(a.flagsB, 1, g, tid);
        __syncthreads();
        if (tid < SLICE) lw_old[tid] = lwn[tid];
    }

    // ===== Main loop: wave-specialized, zero-sync addressing =====
    for (int t = 0; t < TS; t++){
        const int cur = t & 1, nxt = cur ^ 1;

        if (wvi == 0){
            // ---- wave 0: read-addr (full N, in-register) ----
            waitA_wave(a.flagsA, 3 + t, b, lane);
            const float* p = a.rp + (size_t)t*BB*RPL + (size_t)b*RPL;
            float wloc[16];
            wave_addr(p, a.cosr + (size_t)cur*BB*NN + b*NN,
                      a.rdw + (size_t)nxt*BB*NN + b*NN,
                      a.read_w0 + b*NN, (t == 0), lane, wloc);
            if (lane == 0){
                float x0 = p[MM+3+KSH], x1 = p[MM+4+KSH], x2 = p[MM+5+KSH];
                float mx = fmaxf(x0, fmaxf(x1, x2));
                float q0 = expf(x0-mx), q1 = expf(x1-mx), q2 = expf(x2-mx);
                float qs = q0+q1+q2;
                spi[0] = q0/qs; spi[1] = q1/qs; spi[2] = q2/qs;
            }
            if (lane == lbase || lane == lbase+1){
                int j0 = (lane - lbase)*16;
                #pragma unroll
                for (int k = 0; k < 16; k++) swcf_r[j0+k] = wloc[k];
            }
        } else if (wvi == 1){
            // ---- wave 1: write-addr for t+1 ----
            waitA_wave(a.flagsA, 3 + t, b, lane);
            if (t < TS-1){
                const float* p = a.wp + (size_t)(t+1)*BB*WPL + (size_t)b*WPL;
                float wloc[16];
                wave_addr(p, a.cosw + (size_t)nxt*BB*NN + b*NN,
                          a.wbuf + (size_t)cur*BB*NN + b*NN,
                          a.wbuf, 0, lane, wloc);
                if (lane == 0) spi[3] = sigmoidf(p[3*MM+3+KSH]);
                if (lane == lbase || lane == lbase+1){
                    int j0 = (lane - lbase)*16;
                    #pragma unroll
                    for (int k = 0; k < 16; k++) swcf_w[j0+k] = wloc[k];
                }
            }
        } else if (wvi == 2){
            // ---- wave 2: cs/ds gather + bwd/fwd ----
            waitB_wave(a.flagsB, 1 + t, lane);
            int s = lane & 31, hf = lane >> 5;
            float pc = 0.f, pd = 0.f;
            if (s <= t){
                #pragma unroll
                for (int q2 = 0; q2 < 16; q2++){
                    int slc = hf*16 + q2;
                    pc += cload(&a.csp[(size_t)cur*GRID*TS + (size_t)(b*32+slc)*TS + s]);
                    pd += cload(&a.dsp[(size_t)cur*GRID*TS + (size_t)(b*32+slc)*TS + s]);
                }
            }
            pc += __shfl_xor(pc, 32);
            pd += __shfl_xor(pd, 32);
            int j = lane & 31;
            float bwv = 0.f, fwv = 0.f, qq = 0.f;
            for (int s2 = 0; s2 <= t; s2++){
                float av = lA[s2][j], wv = lW[s2][j];
                qq  += av*wv;
                bwv += __shfl(pd, s2)*av;
                fwv += __shfl(pc, s2)*wv;
            }
            if (lane < 32){
                float corr = lr_old[j]*qq;
                lbw[j] = bwv - corr;
                lfw[j] = fwv - corr;
            }
        } else {
            // ---- wave 3: rdp -> out[t-1]; wsum -> prec ----
            waitB_wave(a.flagsB, 1 + t, lane);
            if (t > 0){
                float rv = 0.f;
                #pragma unroll
                for (int q2 = 0; q2 < 4; q2++){
                    int slc = (lane>>3)*4 + q2;
                    rv += cload(&a.rdp[(size_t)nxt*GRID*MM + (size_t)(b*32+slc)*MM + sl*8 + (lane&7)]);
                }
                rv += __shfl_down(rv, 32);
                rv += __shfl_down(rv, 16);
                rv += __shfl_down(rv, 8);
                if (lane < 8) a.out[(size_t)(t-1)*BB*MM + b*MM + sl*8 + lane] = rv;
            }
            if (lane < 32){
                float wsum = 0.f;
                #pragma unroll
                for (int bq = 0; bq < BB; bq++)
                    wsum += cload(&a.wbuf[(size_t)cur*BB*NN + bq*NN + ns0 + lane]);
                lprec[lane] = (1.0f - wsum)*lprec[lane] + lw_old[lane];
            }
        }
        __syncthreads();   // JOIN: swcf/spi/lbw/lfw/lprec visible

        // ---- mix + publish ----
        if (tid < 32){
            int j = tid;
            float v = spi[0]*lbw[j] + spi[1]*swcf_r[j] + spi[2]*lfw[j];
            lrn[j] = v;
            cstore(&a.rdw[(size_t)cur*BB*NN + b*NN + ns0 + j], v);
        } else if (tid >= 64 && tid < 96 && t < TS-1){
            int j = tid - 64;
            float v = (1.0f - spi[3])*swcf_w[j];
            lwn[j] = v;
            cstore(&a.wbuf[(size_t)nxt*BB*NN + b*NN + ns0 + j], v);
        }
        __syncthreads();   // lrn/lwn visible block-wide

        // ---- tail: cos publish -> arriveA; links publish -> arriveB ----
        if (t < TS-1){
            tail_cos(a, t+1, b, g, ns0, lmem, skey, lwn, lrn, tid);
            garrive<false>(a.flagsA, 4 + t, g, tid);
            tail_links(a, t+1, g, lA, lW, lwn, lrn, lprec, tid);
            garrive<false>(a.flagsB, 2 + t, g, tid);
            __syncthreads();
            if (tid < SLICE){ lr_old[tid] = lrn[tid]; lw_old[tid] = lwn[tid]; }
        } else {
            float accv = 0.f;
            #pragma unroll 8
            for (int j = 0; j < SLICE; j++) accv += lrn[j]*lmem[j][tid];
            cstore(&a.rdp[(size_t)1*GRID*MM + g*MM + tid], accv);
            garrive<false>(a.flagsB, 2 + t, g, tid);   // gen TS+1
        }
    }

    // ===== Epilogue: out_31 =====
    gwait<false>(a.flagsB, TS + 1, tid);
    {
        float v = cload(&a.rdp[(size_t)1*GRID*MM + (size_t)(b*32+(tid&31))*MM + sl*8 + (tid>>5)]);
        #pragma unroll
        for (int off = 16; off; off >>= 1) v += __shfl_down(v, off);
        if ((tid & 31) == 0) a.out[(size_t)(TS-1)*BB*MM + b*MM + sl*8 + (tid>>5)] = v;
    }
}

extern "C" void kernel_launch(void* const* d_in, const int* in_sizes, int n_in,
                              void* d_out, int out_size, void* d_ws, size_t ws_size,
                              hipStream_t stream) {
    KArgs ka;
    ka.ctrl     = (const float*)d_in[0];
    ka.rW       = (const float*)d_in[1];
    ka.rb       = (const float*)d_in[2];
    ka.wW       = (const float*)d_in[3];
    ka.wb       = (const float*)d_in[4];
    ka.memory0  = (const float*)d_in[5];
    // d_in[6] = link0: zeros by construction (rank-t factorization assumes L0=0)
    ka.prec0    = (const float*)d_in[7];
    // d_in[8] = usage0: dead (allocation weights identically zero)
    ka.read_w0  = (const float*)d_in[9];
    ka.write_w0 = (const float*)d_in[10];
    ka.out      = (float*)d_out;

    float* ws = (float*)d_ws;
    size_t off = 0;
    auto alloc = [&](size_t n){ float* p = ws + off; off += n; return p; };
    ka.rp    = alloc((size_t)TS*BB*RPL);       // 33920
    ka.wp    = alloc((size_t)TS*BB*WPL);       // 99200
    ka.cosr  = alloc(2*(size_t)BB*NN);
    ka.cosw  = alloc(2*(size_t)BB*NN);
    ka.wbuf  = alloc(2*(size_t)BB*NN);
    ka.rdw   = alloc(2*(size_t)BB*NN);
    ka.csp   = alloc(2*(size_t)GRID*TS);
    ka.dsp   = alloc(2*(size_t)GRID*TS);
    ka.rdp   = alloc(2*(size_t)GRID*MM);       // 65536, coalesced layout
    unsigned* ubase = (unsigned*)(ws + off);
    ka.flagsA = ubase;
    ka.flagsB = ubase + GRID*16;
    size_t bar_bytes = (2*GRID*16) * sizeof(unsigned);

    hipMemsetAsync((void*)ubase, 0, bar_bytes, stream);
    void* params[] = { &ka };
    hipLaunchCooperativeKernel((const void*)kfull, dim3(GRID), dim3(TPB), params, 0, stream);
}